// Round 1
// baseline (7963.840 us; speedup 1.0000x reference)
//
#include <hip/hip_runtime.h>
#include <hip/hip_bf16.h>
#include <math.h>

using bf16 = __hip_bfloat16;
typedef float f32x4 __attribute__((ext_vector_type(4)));
typedef short mfrag __attribute__((ext_vector_type(8)));  // 8 bf16 (4 VGPRs)

#define DEVI __device__ __forceinline__

// async global->LDS, 16B/lane; LDS dest is wave-uniform base + lane*16
DEVI void gll16(const void* g, void* l) {
  __builtin_amdgcn_global_load_lds(
      (const __attribute__((address_space(1))) void*)g,
      (__attribute__((address_space(3))) void*)l, 16, 0, 0);
}

enum { EPI_F32 = 0, EPI_BF16 = 1, EPI_RELU = 2, EPI_RES = 3, EPI_QKV = 4, EPI_OSC = 5 };

struct GArgs {
  const bf16* A; const bf16* B;
  float* Cf; bf16* Cb;
  long sA, sB, sC;          // batch strides (elements)
  int K, lda, ldb, ldc;
  float scale;
  const float* bias; const float* res;
  // conv gather (A side): Cin fixed 512 (shift 9)
  int LoutShift, Lin; const bf16* zp;
  // scatter targets
  bf16 *q, *k, *vt, *o;
};

// ---------------- 128x128x32 bf16 MFMA GEMM: C = A * B^T ----------------
// LDS XOR swizzle: slot (row r, group g in 0..3) holds global col-block g ^ ((r>>1)&3).
// Read bank = (r16&1)*16 + 4*(qd ^ ((r16>>1)&3)) -> 2-way only (free, m136).
template <int EPI, bool GATHER>
__global__ __launch_bounds__(256) void gemm_k(GArgs p) {
  __shared__ alignas(16) bf16 As[128 * 32];
  __shared__ alignas(16) bf16 Bs[128 * 32];
  const int tid = threadIdx.x;
  const int wave = tid >> 6, lane = tid & 63;

  // band-remap block ids for L2 locality: 8 M-tiles per band, N sweeps inside band
  const int nx = gridDim.x, ny = gridDim.y;
  int bid = blockIdx.x + nx * blockIdx.y;
  int band = bid / (nx * 8);
  int rem = bid - band * nx * 8;
  int bh = ny - band * 8; if (bh > 8) bh = 8;
  int nt = rem / bh, mt = band * 8 + (rem - nt * bh);
  const int m0 = mt * 128, n0 = nt * 128;

  const long zb = blockIdx.z;
  const bf16* Ab = p.A + zb * p.sA;
  const bf16* Bb = p.B + zb * p.sB;
  const int sr = tid >> 2;                         // staging row 0..63 (within half)
  const int scol = (((tid & 3) ^ ((sr >> 1) & 3)) * 8);   // swizzled col block
  const int wr = wave >> 1, wcl = wave & 1;
  const int qd = lane >> 4, r16 = lane & 15;
  const int rg = (qd ^ ((r16 >> 1) & 3)) * 8;      // swizzled read group offset (elems)
  char* AsB = (char*)As + wave * 1024;
  char* BsB = (char*)Bs + wave * 1024;

  f32x4 acc[4][4] = {};

  for (int k0 = 0; k0 < p.K; k0 += 32) {
    const bf16 *ga0, *ga1;
    if (GATHER) {
      const int kk = k0 + scol;
      const int tap = kk >> 9, ci = kk & 511;
      const int LoutM = (1 << p.LoutShift) - 1;
      int m1 = m0 + sr;
      int l1 = m1 & LoutM, b1 = m1 >> p.LoutShift;
      int lin1 = 2 * l1 + tap - 1;
      ga0 = ((unsigned)lin1 < (unsigned)p.Lin)
                ? Ab + (((long)(b1 * p.Lin + lin1)) << 9) + ci : p.zp;
      int m2 = m0 + 64 + sr;
      int l2 = m2 & LoutM, b2 = m2 >> p.LoutShift;
      int lin2 = 2 * l2 + tap - 1;
      ga1 = ((unsigned)lin2 < (unsigned)p.Lin)
                ? Ab + (((long)(b2 * p.Lin + lin2)) << 9) + ci : p.zp;
    } else {
      ga0 = Ab + (long)(m0 + sr) * p.lda + k0 + scol;
      ga1 = Ab + (long)(m0 + 64 + sr) * p.lda + k0 + scol;
    }
    const bf16* gb0 = Bb + (long)(n0 + sr) * p.ldb + k0 + scol;
    const bf16* gb1 = Bb + (long)(n0 + 64 + sr) * p.ldb + k0 + scol;
    gll16(ga0, AsB);
    gll16(ga1, AsB + 4096);
    gll16(gb0, BsB);
    gll16(gb1, BsB + 4096);
    __syncthreads();

    mfrag af[4], bfv[4];
#pragma unroll
    for (int i = 0; i < 4; i++)
      af[i] = *(const mfrag*)&As[(wr * 64 + i * 16 + r16) * 32 + rg];
#pragma unroll
    for (int j = 0; j < 4; j++)
      bfv[j] = *(const mfrag*)&Bs[(wcl * 64 + j * 16 + r16) * 32 + rg];
#pragma unroll
    for (int i = 0; i < 4; i++)
#pragma unroll
      for (int j = 0; j < 4; j++)
        acc[i][j] = __builtin_amdgcn_mfma_f32_16x16x32_bf16(af[i], bfv[j], acc[i][j], 0, 0, 0);
    __syncthreads();
  }

  // C/D layout: col=lane&15, row=(lane>>4)*4+reg
  const int erow = m0 + wr * 64 + qd * 4;
#pragma unroll
  for (int j = 0; j < 4; j++) {
    const int gn = n0 + wcl * 64 + j * 16 + r16;
    if constexpr (EPI == EPI_OSC) { if (gn >= 192) continue; }
    float bias_v = 0.f;
    if constexpr (EPI == EPI_RELU) bias_v = p.bias[gn];
    if constexpr (EPI == EPI_RES)  bias_v = p.bias ? p.bias[gn] : 0.f;
    bf16* qkv_base = nullptr; long qkv_coff = 0; int seg = 0;
    if constexpr (EPI == EPI_QKV) {
      int nn;
      if (gn < 1536)      { qkv_base = p.q;  nn = gn; }
      else if (gn < 3072) { qkv_base = p.k;  nn = gn - 1536; }
      else                { qkv_base = p.vt; nn = gn - 3072; seg = 1; }
      const int h = nn / 192, d = nn - h * 192;
      qkv_coff = seg ? ((long)h * 65536 + (long)d * 256)   // vt[bh][d][s] (d rows padded to 256)
                     : ((long)h * 49152 + d);              // q/k[bh][s][d]
    }
#pragma unroll
    for (int i = 0; i < 4; i++) {
#pragma unroll
      for (int v = 0; v < 4; v++) {
        const int gm = erow + i * 16 + v;
        float val = acc[i][j][v] * p.scale;
        if constexpr (EPI == EPI_F32) {
          p.Cf[zb * p.sC + (long)gm * p.ldc + gn] = val;
        } else if constexpr (EPI == EPI_BF16) {
          p.Cb[(long)gm * p.ldc + gn] = (bf16)val;
        } else if constexpr (EPI == EPI_RELU) {
          p.Cb[(long)gm * p.ldc + gn] = (bf16)fmaxf(val + bias_v, 0.f);
        } else if constexpr (EPI == EPI_RES) {
          const long idx = (long)gm * p.ldc + gn;
          p.Cf[idx] = val + bias_v + p.res[idx];
        } else if constexpr (EPI == EPI_QKV) {
          const int bq = gm >> 8, s = gm & 255;
          const long idx = seg ? (qkv_coff + (long)bq * 524288 + s)
                               : (qkv_coff + (long)bq * 393216 + (long)s * 192);
          qkv_base[idx] = (bf16)val;
        } else if constexpr (EPI == EPI_OSC) {
          const int bq = (int)(zb >> 3), h = (int)(zb & 7);
          p.o[((long)bq * 256 + gm) * 1536 + h * 192 + gn] = (bf16)val;
        }
      }
    }
  }
}

// ---------------- conv0: (B,14,8192) fp32 -> Y (B*4096, 512) bf16 channels-last -------------
__global__ __launch_bounds__(256) void conv0_k(const float* __restrict__ x,
                                               const float* __restrict__ w, bf16* Y) {
  const int b = blockIdx.y, l0 = blockIdx.x * 16;
  __shared__ float xs[14 * 33];
  const int t = threadIdx.x;
  for (int i = t; i < 14 * 33; i += 256) {
    int ci = i / 33, pp = i - ci * 33;
    int pos = 2 * l0 - 1 + pp;
    xs[i] = (pos >= 0 && pos < 8192) ? x[((long)b * 14 + ci) * 8192 + pos] : 0.f;
  }
  float wr0[42], wr1[42];
  const int co0 = 2 * t;
#pragma unroll
  for (int i = 0; i < 42; i++) { wr0[i] = w[co0 * 42 + i]; wr1[i] = w[co0 * 42 + 42 + i]; }
  __syncthreads();
  for (int l = 0; l < 16; l++) {
    float a0 = 0.f, a1 = 0.f;
#pragma unroll
    for (int ci = 0; ci < 14; ci++)
#pragma unroll
      for (int k = 0; k < 3; k++) {
        float xv = xs[ci * 33 + 2 * l + k];
        a0 += xv * wr0[ci * 3 + k];
        a1 += xv * wr1[ci * 3 + k];
      }
    long orow = ((long)b * 4096 + l0 + l) * 512;
    Y[orow + co0] = (bf16)a0;
    Y[orow + co0 + 1] = (bf16)a1;
  }
}

// ---------------- BN stats ----------------
__global__ void bn_stats_k(const bf16* __restrict__ Y, float* stats, int rows, int C) {
  const int c = blockIdx.x * 256 + threadIdx.x;
  const int rpb = rows / gridDim.y;
  const int r0 = blockIdx.y * rpb;
  float s = 0.f, ss = 0.f;
  const bf16* p = Y + (long)r0 * C + c;
  for (int r = 0; r < rpb; ++r) { float v = (float)(*p); s += v; ss += v * v; p += C; }
  atomicAdd(&stats[2 * c], s);
  atomicAdd(&stats[2 * c + 1], ss);
}

// ---------------- fused BN (train-mode) + exact-erf GELU (in-place capable) -------------
__global__ void bn_gelu_k(const bf16* __restrict__ Y, const float* __restrict__ stats,
                          const float* __restrict__ g, const float* __restrict__ be,
                          bf16* outB, float* outF, long n, int C, float invN) {
  long i = blockIdx.x * 256L + threadIdx.x;
  const long st = (long)gridDim.x * 256;
  for (; i < n; i += st) {
    int c = (int)(i % C);
    float m = stats[2 * c] * invN;
    float var = stats[2 * c + 1] * invN - m * m;
    float rs = rsqrtf(fmaxf(var, 0.f) + 1e-5f);
    float xn = ((float)Y[i] - m) * rs * g[c] + be[c];
    float ge = 0.5f * xn * (1.f + erff(xn * 0.70710678118f));
    outB[i] = (bf16)ge;
    if (outF) outF[i] = ge;
  }
}

// ---------------- LayerNorm over E=1536 ----------------
__global__ __launch_bounds__(256) void ln_k(const float* __restrict__ in,
                                            const float* __restrict__ g,
                                            const float* __restrict__ b,
                                            float* outF, bf16* outB) {
  const int row = blockIdx.x, t = threadIdx.x;
  const float* r = in + (long)row * 1536;
  float v[6]; float s = 0.f;
#pragma unroll
  for (int i = 0; i < 6; i++) { v[i] = r[t + 256 * i]; s += v[i]; }
  __shared__ float red[256];
  red[t] = s; __syncthreads();
#pragma unroll
  for (int o = 128; o > 0; o >>= 1) { if (t < o) red[t] += red[t + o]; __syncthreads(); }
  const float mean = red[0] * (1.f / 1536.f);
  __syncthreads();
  float ss = 0.f;
#pragma unroll
  for (int i = 0; i < 6; i++) { float d = v[i] - mean; ss += d * d; }
  red[t] = ss; __syncthreads();
#pragma unroll
  for (int o = 128; o > 0; o >>= 1) { if (t < o) red[t] += red[t + o]; __syncthreads(); }
  const float rstd = rsqrtf(red[0] * (1.f / 1536.f) + 1e-5f);
#pragma unroll
  for (int i = 0; i < 6; i++) {
    int c = t + 256 * i;
    float o_ = (v[i] - mean) * rstd * g[c] + b[c];
    if (outF) outF[(long)row * 1536 + c] = o_;
    if (outB) outB[(long)row * 1536 + c] = (bf16)o_;
  }
}

// ---------------- softmax over rows of 256 (one wave per row) ----------------
__global__ void softmax_k(const float* __restrict__ sc, bf16* P) {
  const int row = blockIdx.x * 4 + (threadIdx.x >> 6);
  const int lane = threadIdx.x & 63;
  const float* r = sc + (long)row * 256;
  float v0 = r[lane], v1 = r[lane + 64], v2 = r[lane + 128], v3 = r[lane + 192];
  float mx = fmaxf(fmaxf(v0, v1), fmaxf(v2, v3));
  for (int m = 32; m > 0; m >>= 1) mx = fmaxf(mx, __shfl_xor(mx, m));
  v0 = expf(v0 - mx); v1 = expf(v1 - mx); v2 = expf(v2 - mx); v3 = expf(v3 - mx);
  float s = v0 + v1 + v2 + v3;
  for (int m = 32; m > 0; m >>= 1) s += __shfl_xor(s, m);
  const float inv = 1.f / s;
  bf16* o = P + (long)row * 256;
  o[lane] = (bf16)(v0 * inv); o[lane + 64] = (bf16)(v1 * inv);
  o[lane + 128] = (bf16)(v2 * inv); o[lane + 192] = (bf16)(v3 * inv);
}

// ---------------- packing (per-layer, reused buffers) ----------------
__global__ void zero_k(float* p, int n) {
  int i = blockIdx.x * 256 + threadIdx.x;
  if (i < n) p[i] = 0.f;
}

__global__ void pack_qkv_k(const float* wq, const float* wk, const float* wv, bf16* out) {
  const int c = blockIdx.x * 256 + threadIdx.x;   // 0..1535
  const int r = blockIdx.y;                        // 0..4607
  const float* src; int rr;
  if (r < 1536) { src = wq; rr = r; }
  else if (r < 3072) { src = wk; rr = r - 1536; }
  else { src = wv; rr = r - 3072; }
  out[(long)r * 1536 + c] = (bf16)src[(long)rr * 1536 + c];
}

__global__ void cast_k(const float* in, bf16* out, long n) {
  long i = blockIdx.x * 256L + threadIdx.x;
  const long st = (long)gridDim.x * 256;
  for (; i < n; i += st) out[i] = (bf16)in[i];
}

__global__ void pack_w1_k(const float* w1, bf16* out) {
  const int c = blockIdx.x * 256 + threadIdx.x;
  const int r = blockIdx.y;                        // 0..3199
  float v = (r < 3076) ? w1[(long)r * 1536 + c] : 0.f;
  out[(long)r * 1536 + c] = (bf16)v;
}

__global__ void pack_w2_k(const float* w2, bf16* out) {
  const int c = blockIdx.x * 128 + threadIdx.x;    // 0..3199
  const int r = blockIdx.y;
  float v = (c < 3076) ? w2[(long)r * 3076 + c] : 0.f;
  out[(long)r * 3200 + c] = (bf16)v;
}

__global__ void pack_b1_k(const float* b1, float* out) {
  const int c = blockIdx.x * 128 + threadIdx.x;
  const int l = blockIdx.y;
  out[l * 3200 + c] = (c < 3076) ? b1[l * 3076 + c] : 0.f;
}

// conv weight: (Cout, 512, 3) fp32 -> (Cout, 3*512) bf16, kappa = k*512+ci
__global__ void pack_conv_k(const float* w, bf16* out) {
  const int co = blockIdx.x;
  for (int i = threadIdx.x; i < 1536; i += 256) {
    int k = i >> 9, ci = i & 511;
    out[(long)co * 1536 + i] = (bf16)w[(co * 512 + ci) * 3 + k];
  }
}

// =====================================================================================
extern "C" void kernel_launch(void* const* d_in, const int* in_sizes, int n_in,
                              void* d_out, int out_size, void* d_ws, size_t ws_size,
                              hipStream_t stream) {
  const float* x_in = (const float*)d_in[0];
  const float *cw[5], *gg[5], *bb[5];
  for (int i = 0; i < 5; i++) {
    cw[i] = (const float*)d_in[1 + 4 * i];
    gg[i] = (const float*)d_in[3 + 4 * i];
    bb[i] = (const float*)d_in[4 + 4 * i];
  }
  const float* wq = (const float*)d_in[21];
  const float* wk = (const float*)d_in[22];
  const float* wv = (const float*)d_in[23];
  const float* wo = (const float*)d_in[24];
  const float* w1 = (const float*)d_in[25];
  const float* b1 = (const float*)d_in[26];
  const float* w2 = (const float*)d_in[27];
  const float* b2 = (const float*)d_in[28];
  const float* ln1g = (const float*)d_in[29];
  const float* ln1b = (const float*)d_in[30];
  const float* ln2g = (const float*)d_in[31];
  const float* ln2b = (const float*)d_in[32];

  char* ws = (char*)d_ws;
  size_t off = 0;
  auto alloc = [&](size_t bytes) -> char* {
    off = (off + 255) & ~(size_t)255;
    char* p = ws + off; off += bytes; return p;
  };
  // ---- small fixed buffers ----
  bf16* zp = (bf16*)alloc(256);
  float* stats = (float*)alloc(3072 * 4);
  float* b1p = (float*)alloc(8L * 3200 * 4);
  // ---- per-layer weight buffers (re-packed each layer) ----
  bf16* wqkv_l = (bf16*)alloc(4608L * 1536 * 2);   // 14.2 MB
  bf16* wo_l   = (bf16*)alloc(1536L * 1536 * 2);   //  4.7 MB
  bf16* w1_l   = (bf16*)alloc(3200L * 1536 * 2);   //  9.8 MB
  bf16* w2_l   = (bf16*)alloc(1536L * 3200 * 2);   //  9.8 MB
  bf16* wconv  = (bf16*)alloc(1536L * 1536 * 2);   //  4.7 MB (per-conv)
  // ---- big aliased activation buffers ----
  char* A = alloc(134217728);                      // 134.2 MB
  char* Bq = alloc(67108864);                      //  67.1 MB
  bf16* xb = (bf16*)alloc(8192L * 1536 * 2);       //  25.2 MB
  // total ~270 MB. xf (fp32 residual) lives in d_out (48 MB).
  float* xf = (float*)d_out;

  // attn-phase aliases
  bf16*  vtb    = (bf16*)A;                        // [0, 33.5M)
  float* scores = (float*)(A + 33554432);          // [33.5M, 100.7M)
  bf16*  P      = (bf16*)(A + 100663296);          // [100.7M, 134.2M)
  bf16*  qb     = (bf16*)Bq;                       // [0, 25.2M)
  bf16*  kb     = (bf16*)(Bq + 25165824);          // [25.2M, 50.3M)
  bf16*  ob     = (bf16*)Bq;                       // overwrites q (dead after QK)
  // ffn-phase aliases
  float* rf  = (float*)A;                          // [0, 50.3M)
  bf16*  hb  = (bf16*)(A + 50331648);              // [50.3M, 75.5M)
  bf16*  mid = (bf16*)(A + 75497472);              // [75.5M, 127.9M)
  float* hf  = (float*)Bq;                         // [0, 50.3M)
  // conv-phase aliases
  bf16* cY0 = (bf16*)A;    // conv0 out 131072x512
  bf16* cY1 = (bf16*)Bq;   // conv1 out 65536x512
  bf16* cY2 = (bf16*)A;    // conv2 out 32768x512
  bf16* cY3 = (bf16*)Bq;   // conv3 out 16384x512
  bf16* cY4 = (bf16*)A;    // conv4 out 8192x1536

  zero_k<<<1, 256, 0, stream>>>((float*)zp, 64);
  pack_b1_k<<<dim3(25, 8), 128, 0, stream>>>(b1, b1p);

  conv0_k<<<dim3(256, 32), 256, 0, stream>>>(x_in, cw[0], cY0);

  auto bn = [&](const bf16* Y, bf16* outB, float* outF, int rows, int C,
                const float* g_, const float* be_) {
    zero_k<<<12, 256, 0, stream>>>(stats, 3072);
    bn_stats_k<<<dim3(C / 256, 256), 256, 0, stream>>>(Y, stats, rows, C);
    bn_gelu_k<<<4096, 256, 0, stream>>>(Y, stats, g_, be_, outB, outF,
                                        (long)rows * C, C, 1.f / (float)rows);
  };
  auto conv_gemm = [&](const bf16* Gin, const float* wsrc, int Cout, bf16* Yout,
                       int M, int N, int LoutShift, int Lin) {
    pack_conv_k<<<Cout, 256, 0, stream>>>(wsrc, wconv);
    GArgs a{}; a.A = Gin; a.B = wconv; a.Cb = Yout;
    a.K = 1536; a.ldb = 1536; a.ldc = N; a.scale = 1.f;
    a.LoutShift = LoutShift; a.Lin = Lin; a.zp = zp;
    gemm_k<EPI_BF16, true><<<dim3(N / 128, M / 128, 1), 256, 0, stream>>>(a);
  };

  bn(cY0, cY0, nullptr, 131072, 512, gg[0], bb[0]);          // in-place BN+GELU
  conv_gemm(cY0, cw[1], 512, cY1, 65536, 512, 11, 4096);
  bn(cY1, cY1, nullptr, 65536, 512, gg[1], bb[1]);
  conv_gemm(cY1, cw[2], 512, cY2, 32768, 512, 10, 2048);
  bn(cY2, cY2, nullptr, 32768, 512, gg[2], bb[2]);
  conv_gemm(cY2, cw[3], 512, cY3, 16384, 512, 9, 1024);
  bn(cY3, cY3, nullptr, 16384, 512, gg[3], bb[3]);
  conv_gemm(cY3, cw[4], 1536, cY4, 8192, 1536, 8, 512);
  bn(cY4, xb, xf, 8192, 1536, gg[4], bb[4]);                 // -> (B,S,E) bf16 + fp32

  for (int l = 0; l < 8; l++) {
    // per-layer weight packing (stream-serialized, reused buffers)
    pack_qkv_k<<<dim3(6, 4608), 256, 0, stream>>>(wq + (long)l * 1536 * 1536,
                                                  wk + (long)l * 1536 * 1536,
                                                  wv + (long)l * 1536 * 1536, wqkv_l);
    cast_k<<<2048, 256, 0, stream>>>(wo + (long)l * 1536 * 1536, wo_l, 1536L * 1536);
    pack_w1_k<<<dim3(6, 3200), 256, 0, stream>>>(w1 + (long)l * 3076 * 1536, w1_l);
    pack_w2_k<<<dim3(25, 1536), 128, 0, stream>>>(w2 + (long)l * 1536 * 3076, w2_l);

    { // fused QKV projection, scatter into q/k (bh,s,d) and vt (bh,d,s)
      GArgs a{}; a.A = xb; a.B = wqkv_l;
      a.K = 1536; a.lda = 1536; a.ldb = 1536; a.scale = 1.f;
      a.q = qb; a.k = kb; a.vt = vtb;
      gemm_k<EPI_QKV, false><<<dim3(36, 64, 1), 256, 0, stream>>>(a);
    }
    { // scores = Q K^T / sqrt(192), batched over 256 (b,h)
      GArgs a{}; a.A = qb; a.B = kb; a.Cf = scores;
      a.sA = 49152; a.sB = 49152; a.sC = 65536;
      a.K = 192; a.lda = 192; a.ldb = 192; a.ldc = 256;
      a.scale = 0.07216878364870323f;
      gemm_k<EPI_F32, false><<<dim3(2, 2, 256), 256, 0, stream>>>(a);
    }
    softmax_k<<<16384, 256, 0, stream>>>(scores, P);
    { // O = P V via vt; scatter into ob (b,s,e)
      GArgs a{}; a.A = P; a.B = vtb; a.sA = 65536; a.sB = 65536;
      a.K = 256; a.lda = 256; a.ldb = 256; a.scale = 1.f; a.o = ob;
      gemm_k<EPI_OSC, false><<<dim3(2, 2, 256), 256, 0, stream>>>(a);
    }
    { // rf = ob @ wo^T + xf
      GArgs a{}; a.A = ob; a.B = wo_l; a.Cf = rf;
      a.K = 1536; a.lda = 1536; a.ldb = 1536; a.ldc = 1536; a.scale = 1.f;
      a.bias = nullptr; a.res = xf;
      gemm_k<EPI_RES, false><<<dim3(12, 64, 1), 256, 0, stream>>>(a);
    }
    ln_k<<<8192, 256, 0, stream>>>(rf, ln1g + l * 1536, ln1b + l * 1536, hf, hb);
    { // mid = relu(hb @ w1^T + b1), N padded to 3200
      GArgs a{}; a.A = hb; a.B = w1_l; a.Cb = mid;
      a.K = 1536; a.lda = 1536; a.ldb = 1536; a.ldc = 3200; a.scale = 1.f;
      a.bias = b1p + l * 3200;
      gemm_k<EPI_RELU, false><<<dim3(25, 64, 1), 256, 0, stream>>>(a);
    }
    { // rf = mid @ w2^T + b2 + hf
      GArgs a{}; a.A = mid; a.B = w2_l; a.Cf = rf;
      a.K = 3200; a.lda = 3200; a.ldb = 3200; a.ldc = 1536; a.scale = 1.f;
      a.bias = b2 + l * 1536; a.res = hf;
      gemm_k<EPI_RES, false><<<dim3(12, 64, 1), 256, 0, stream>>>(a);
    }
    if (l < 7)
      ln_k<<<8192, 256, 0, stream>>>(rf, ln2g + l * 1536, ln2b + l * 1536, xf, xb);
    else
      ln_k<<<8192, 256, 0, stream>>>(rf, ln2g + l * 1536, ln2b + l * 1536,
                                     (float*)d_out, nullptr);
  }
}

// Round 3
// 6754.239 us; speedup vs baseline: 1.1791x; 1.1791x over previous
//
#include <hip/hip_runtime.h>
#include <hip/hip_bf16.h>
#include <math.h>

using bf16 = __hip_bfloat16;
typedef float f32x4 __attribute__((ext_vector_type(4)));
typedef short mfrag __attribute__((ext_vector_type(8)));  // 8 bf16 (4 VGPRs)

#define DEVI __device__ __forceinline__

// async global->LDS, 16B/lane; LDS dest is wave-uniform base + lane*16
DEVI void gll16(const void* g, void* l) {
  __builtin_amdgcn_global_load_lds(
      (const __attribute__((address_space(1))) void*)g,
      (__attribute__((address_space(3))) void*)l, 16, 0, 0);
}

// raw barrier + full sched fence: no memory op may be moved across the barrier
// (s_barrier intrinsic is IntrNoMem -> compiler could otherwise hoist ds_reads
// into the window where other waves' global_load_lds are still landing)
DEVI void barx() {
  __builtin_amdgcn_s_barrier();
  __builtin_amdgcn_sched_barrier(0);
}
#define LGKM0() asm volatile("s_waitcnt lgkmcnt(0)" ::: "memory")
#define VMCNT2() asm volatile("s_waitcnt vmcnt(2)" ::: "memory")
#define VMCNT0() asm volatile("s_waitcnt vmcnt(0)" ::: "memory")

enum { EPI_F32 = 0, EPI_BF16 = 1, EPI_RELU = 2, EPI_RES = 3, EPI_QKV = 4, EPI_OSC = 5 };

struct GArgs {
  const bf16* A; const bf16* B;
  float* Cf; bf16* Cb;
  long sA, sB, sC;          // batch strides (elements)
  int K, lda, ldb, ldc;
  float scale;
  const float* bias; const float* res;
  // conv gather (A side): Cin fixed 512 (shift 9)
  int LoutShift, Lin; const bf16* zp;
  // scatter targets
  bf16 *q, *k, *vt, *o;
};

// =====================================================================================
// 256x256x64 8-phase bf16 MFMA GEMM (T2+T3+T4+T5): C = A * B^T
// 8 waves (2M x 4N), per-wave 128x64 out. LDS 128KB static: 2 buf x (A 32KB + B 32KB).
// Tile rows 256 x 64 K-elems (128B/row). XOR swizzle: LDS 16B-slot s of row r holds
// global slot s ^ (r&7); staged via inverse-swizzled GLOBAL source (linear LDS dest,
// rule #21); ds_read col byte = (desired slot ^ (r&7))*16 -> even 32-bank spread.
// Counted vmcnt: stage order per tile [B0 B1][B2 B3][A0 A2][A1 A3]; phase0 needs the
// 6 oldest -> vmcnt(2) at tile entry; phase1 needs A1,A3 -> vmcnt(2) after ph0's
// 2 new stages. Never drain to 0 except final tile.
// =====================================================================================
template <int EPI, bool GATHER>
__global__ __launch_bounds__(512, 2) void gemm256_k(GArgs p) {
  __shared__ char sm[131072];
  const int tid = threadIdx.x;
  const int wave = tid >> 6, lane = tid & 63;
  const int wm = wave >> 2, wn = wave & 3;
  const int qd = lane >> 4, r16 = lane & 15;

  // bijective XCD-chunked remap
  const int ntN = gridDim.x;
  const int total = ntN * gridDim.y;
  const int bid = blockIdx.x + ntN * blockIdx.y;
  const int q8 = total >> 3, r8 = total & 7;
  const int xcd = bid & 7, idx = bid >> 3;
  const int wg = (xcd < r8 ? xcd * (q8 + 1) : r8 * (q8 + 1) + (xcd - r8) * q8) + idx;
  const int mt = wg / ntN, nt = wg - mt * ntN;
  const int m0 = mt * 256, n0 = nt * 256;

  const bf16* Ab = p.A;
  const bf16* Bb = p.B;

  // ---- staging constants (thread t covers row rowt, 16B slot `slot` of a 64-row chunk)
  const int rowt = tid >> 3;
  const int slot = tid & 7;
  const int cs8 = (slot ^ (rowt & 7)) * 8;      // inverse-swizzled global col (elems)
  const int woff = wave * 1024;                 // wave slice of an 8KB chunk

  auto stA = [&](char* dstA, int c, int k) {
    const bf16* s;
    if constexpr (GATHER) {
      const int row = m0 + c * 64 + rowt;
      const int col = k + cs8;
      const int LoutM = (1 << p.LoutShift) - 1;
      const int l = row & LoutM, b = row >> p.LoutShift;
      const int tap = col >> 9, ci = col & 511;
      const int lin = 2 * l + tap - 1;
      s = ((unsigned)lin < (unsigned)p.Lin)
              ? Ab + (((long)(b * p.Lin + lin)) << 9) + ci : p.zp;
    } else {
      s = Ab + (long)(m0 + c * 64 + rowt) * p.lda + k + cs8;
    }
    gll16(s, dstA + c * 8192 + woff);
  };
  auto stB = [&](char* dstB, int c, int k) {
    gll16(Bb + (long)(n0 + c * 64 + rowt) * p.ldb + k + cs8, dstB + c * 8192 + woff);
  };

  // ---- ds_read constants
  const int xw = (r16 & 7) << 4;
  const int c0 = (qd * 16) ^ xw;                // ks=0 col byte (swizzled)
  const int c1 = (qd * 16 + 64) ^ xw;           // ks=1 col byte (swizzled)
  const int rbA = (wm * 128 + r16) * 128;       // A row base byte (within A region)
  const int rbB = 32768 + (wn * 64 + r16) * 128;// B row base byte

  f32x4 acc[8][4] = {};
  const int NT = p.K >> 6;

  // ---- prologue: stage tile 0 into buf0, order B0 B1 B2 B3 A0 A2 A1 A3
  {
    char* dA = sm;
    char* dB = sm + 32768;
    stB(dB, 0, 0); stB(dB, 1, 0); stB(dB, 2, 0); stB(dB, 3, 0);
    stA(dA, 0, 0); stA(dA, 2, 0); stA(dA, 1, 0); stA(dA, 3, 0);
  }
  VMCNT2();   // 6 oldest chunks (B0-3, A0, A2) resident
  barx();

  for (int t = 0; t < NT; ++t) {
    char* bc = sm + (t & 1) * 65536;
    char* bnA = sm + ((t & 1) ^ 1) * 65536;
    char* bnB = bnA + 32768;
    const int k1 = (t + 1) << 6;
    const bool notlast = (t + 1 < NT);

    mfrag af[4], bf[4];

    // ---------- phase 0: mh=0 ks=0 (A + B reads) ----------
    {
      const char* aB = bc + rbA;
      af[0] = *(const mfrag*)(aB + 0 * 2048 + c0);
      af[1] = *(const mfrag*)(aB + 1 * 2048 + c0);
      af[2] = *(const mfrag*)(aB + 2 * 2048 + c0);
      af[3] = *(const mfrag*)(aB + 3 * 2048 + c0);
      const char* bB = bc + rbB;
      bf[0] = *(const mfrag*)(bB + 0 * 2048 + c0);
      bf[1] = *(const mfrag*)(bB + 1 * 2048 + c0);
      bf[2] = *(const mfrag*)(bB + 2 * 2048 + c0);
      bf[3] = *(const mfrag*)(bB + 3 * 2048 + c0);
      if (notlast) { stB(bnB, 0, k1); stB(bnB, 1, k1); }
      barx();
      __builtin_amdgcn_s_setprio(1);
#pragma unroll
      for (int i2 = 0; i2 < 4; i2++)
#pragma unroll
        for (int j = 0; j < 4; j++)
          acc[i2][j] = __builtin_amdgcn_mfma_f32_16x16x32_bf16(af[i2], bf[j], acc[i2][j], 0, 0, 0);
      __builtin_amdgcn_s_setprio(0);
      LGKM0();
      if (notlast) VMCNT2(); else VMCNT0();   // A1,A3 of THIS tile now resident
      barx();
    }
    // ---------- phase 1: mh=1 ks=0 (A reads only, B reuse) ----------
    {
      const char* aB = bc + rbA + 8192;
      af[0] = *(const mfrag*)(aB + 0 * 2048 + c0);
      af[1] = *(const mfrag*)(aB + 1 * 2048 + c0);
      af[2] = *(const mfrag*)(aB + 2 * 2048 + c0);
      af[3] = *(const mfrag*)(aB + 3 * 2048 + c0);
      if (notlast) { stB(bnB, 2, k1); stB(bnB, 3, k1); }
      barx();
      __builtin_amdgcn_s_setprio(1);
#pragma unroll
      for (int i2 = 0; i2 < 4; i2++)
#pragma unroll
        for (int j = 0; j < 4; j++)
          acc[4 + i2][j] = __builtin_amdgcn_mfma_f32_16x16x32_bf16(af[i2], bf[j], acc[4 + i2][j], 0, 0, 0);
      __builtin_amdgcn_s_setprio(0);
      LGKM0();
      barx();
    }
    // ---------- phase 2: mh=0 ks=1 (A + B reads) ----------
    {
      const char* aB = bc + rbA;
      af[0] = *(const mfrag*)(aB + 0 * 2048 + c1);
      af[1] = *(const mfrag*)(aB + 1 * 2048 + c1);
      af[2] = *(const mfrag*)(aB + 2 * 2048 + c1);
      af[3] = *(const mfrag*)(aB + 3 * 2048 + c1);
      const char* bB = bc + rbB;
      bf[0] = *(const mfrag*)(bB + 0 * 2048 + c1);
      bf[1] = *(const mfrag*)(bB + 1 * 2048 + c1);
      bf[2] = *(const mfrag*)(bB + 2 * 2048 + c1);
      bf[3] = *(const mfrag*)(bB + 3 * 2048 + c1);
      if (notlast) { stA(bnA, 0, k1); stA(bnA, 2, k1); }
      barx();
      __builtin_amdgcn_s_setprio(1);
#pragma unroll
      for (int i2 = 0; i2 < 4; i2++)
#pragma unroll
        for (int j = 0; j < 4; j++)
          acc[i2][j] = __builtin_amdgcn_mfma_f32_16x16x32_bf16(af[i2], bf[j], acc[i2][j], 0, 0, 0);
      __builtin_amdgcn_s_setprio(0);
      LGKM0();
      barx();
    }
    // ---------- phase 3: mh=1 ks=1 (A reads only) ----------
    {
      const char* aB = bc + rbA + 8192;
      af[0] = *(const mfrag*)(aB + 0 * 2048 + c1);
      af[1] = *(const mfrag*)(aB + 1 * 2048 + c1);
      af[2] = *(const mfrag*)(aB + 2 * 2048 + c1);
      af[3] = *(const mfrag*)(aB + 3 * 2048 + c1);
      if (notlast) { stA(bnA, 1, k1); stA(bnA, 3, k1); }
      barx();
      __builtin_amdgcn_s_setprio(1);
#pragma unroll
      for (int i2 = 0; i2 < 4; i2++)
#pragma unroll
        for (int j = 0; j < 4; j++)
          acc[4 + i2][j] = __builtin_amdgcn_mfma_f32_16x16x32_bf16(af[i2], bf[j], acc[4 + i2][j], 0, 0, 0);
      __builtin_amdgcn_s_setprio(0);
      LGKM0();
      if (notlast) VMCNT2();                   // B0-3,A0,A2 of NEXT tile resident
      barx();
    }
  }

  // ---- epilogue. C/D layout: col=lane&15, row=(lane>>4)*4+reg
  const int erow = m0 + wm * 128 + qd * 4;
#pragma unroll
  for (int j = 0; j < 4; j++) {
    const int gn = n0 + wn * 64 + j * 16 + r16;
    float bias_v = 0.f;
    if constexpr (EPI == EPI_RELU) bias_v = p.bias[gn];
    if constexpr (EPI == EPI_RES)  bias_v = p.bias ? p.bias[gn] : 0.f;
    bf16* qkv_base = nullptr; long qkv_coff = 0; int seg = 0;
    if constexpr (EPI == EPI_QKV) {
      int nn;
      if (gn < 1536)      { qkv_base = p.q;  nn = gn; }
      else if (gn < 3072) { qkv_base = p.k;  nn = gn - 1536; }
      else                { qkv_base = p.vt; nn = gn - 3072; seg = 1; }
      const int h = nn / 192, d = nn - h * 192;
      qkv_coff = seg ? ((long)h * 65536 + (long)d * 256)   // vt[bh][d][s]
                     : ((long)h * 49152 + d);              // q/k[bh][s][d]
    }
#pragma unroll
    for (int i = 0; i < 8; i++) {
#pragma unroll
      for (int v = 0; v < 4; v++) {
        const int gm = erow + i * 16 + v;
        float val = acc[i][j][v] * p.scale;
        if constexpr (EPI == EPI_BF16) {
          p.Cb[(long)gm * p.ldc + gn] = (bf16)val;
        } else if constexpr (EPI == EPI_RELU) {
          p.Cb[(long)gm * p.ldc + gn] = (bf16)fmaxf(val + bias_v, 0.f);
        } else if constexpr (EPI == EPI_RES) {
          const long idx = (long)gm * p.ldc + gn;
          p.Cf[idx] = val + bias_v + p.res[idx];
        } else if constexpr (EPI == EPI_QKV) {
          const int bq = gm >> 8, s = gm & 255;
          const long idx = seg ? (qkv_coff + (long)bq * 524288 + s)
                               : (qkv_coff + (long)bq * 393216 + (long)s * 192);
          qkv_base[idx] = (bf16)val;
        }
      }
    }
  }
}

// ---------------- 128x128x32 bf16 MFMA GEMM (kept for small attention GEMMs) --------
template <int EPI, bool GATHER>
__global__ __launch_bounds__(256) void gemm_k(GArgs p) {
  __shared__ alignas(16) bf16 As[128 * 32];
  __shared__ alignas(16) bf16 Bs[128 * 32];
  const int tid = threadIdx.x;
  const int wave = tid >> 6, lane = tid & 63;

  const int nx = gridDim.x, ny = gridDim.y;
  int bid = blockIdx.x + nx * blockIdx.y;
  int band = bid / (nx * 8);
  int rem = bid - band * nx * 8;
  int bh = ny - band * 8; if (bh > 8) bh = 8;
  int nt = rem / bh, mt = band * 8 + (rem - nt * bh);
  const int m0 = mt * 128, n0 = nt * 128;

  const long zb = blockIdx.z;
  const bf16* Ab = p.A + zb * p.sA;
  const bf16* Bb = p.B + zb * p.sB;
  const int sr = tid >> 2;
  const int scol = (((tid & 3) ^ ((sr >> 1) & 3)) * 8);
  const int wr = wave >> 1, wcl = wave & 1;
  const int qd = lane >> 4, r16 = lane & 15;
  const int rg = (qd ^ ((r16 >> 1) & 3)) * 8;
  char* AsB = (char*)As + wave * 1024;
  char* BsB = (char*)Bs + wave * 1024;

  f32x4 acc[4][4] = {};

  for (int k0 = 0; k0 < p.K; k0 += 32) {
    const bf16 *ga0, *ga1;
    if (GATHER) {
      const int kk = k0 + scol;
      const int tap = kk >> 9, ci = kk & 511;
      const int LoutM = (1 << p.LoutShift) - 1;
      int m1 = m0 + sr;
      int l1 = m1 & LoutM, b1 = m1 >> p.LoutShift;
      int lin1 = 2 * l1 + tap - 1;
      ga0 = ((unsigned)lin1 < (unsigned)p.Lin)
                ? Ab + (((long)(b1 * p.Lin + lin1)) << 9) + ci : p.zp;
      int m2 = m0 + 64 + sr;
      int l2 = m2 & LoutM, b2 = m2 >> p.LoutShift;
      int lin2 = 2 * l2 + tap - 1;
      ga1 = ((unsigned)lin2 < (unsigned)p.Lin)
                ? Ab + (((long)(b2 * p.Lin + lin2)) << 9) + ci : p.zp;
    } else {
      ga0 = Ab + (long)(m0 + sr) * p.lda + k0 + scol;
      ga1 = Ab + (long)(m0 + 64 + sr) * p.lda + k0 + scol;
    }
    const bf16* gb0 = Bb + (long)(n0 + sr) * p.ldb + k0 + scol;
    const bf16* gb1 = Bb + (long)(n0 + 64 + sr) * p.ldb + k0 + scol;
    gll16(ga0, AsB);
    gll16(ga1, AsB + 4096);
    gll16(gb0, BsB);
    gll16(gb1, BsB + 4096);
    __syncthreads();

    mfrag af[4], bfv[4];
#pragma unroll
    for (int i = 0; i < 4; i++)
      af[i] = *(const mfrag*)&As[(wr * 64 + i * 16 + r16) * 32 + rg];
#pragma unroll
    for (int j = 0; j < 4; j++)
      bfv[j] = *(const mfrag*)&Bs[(wcl * 64 + j * 16 + r16) * 32 + rg];
#pragma unroll
    for (int i = 0; i < 4; i++)
#pragma unroll
      for (int j = 0; j < 4; j++)
        acc[i][j] = __builtin_amdgcn_mfma_f32_16x16x32_bf16(af[i], bfv[j], acc[i][j], 0, 0, 0);
    __syncthreads();
  }

  const int erow = m0 + wr * 64 + qd * 4;
#pragma unroll
  for (int j = 0; j < 4; j++) {
    const int gn = n0 + wcl * 64 + j * 16 + r16;
    if constexpr (EPI == EPI_OSC) { if (gn >= 192) continue; }
#pragma unroll
    for (int i = 0; i < 4; i++) {
#pragma unroll
      for (int v = 0; v < 4; v++) {
        const int gm = erow + i * 16 + v;
        float val = acc[i][j][v] * p.scale;
        if constexpr (EPI == EPI_F32) {
          p.Cf[zb * p.sC + (long)gm * p.ldc + gn] = val;
        } else if constexpr (EPI == EPI_OSC) {
          const int bq = (int)(zb >> 3), h = (int)(zb & 7);
          p.o[((long)bq * 256 + gm) * 1536 + h * 192 + gn] = (bf16)val;
        }
      }
    }
  }
}

// ---------------- conv0: (B,14,8192) fp32 -> Y (B*4096, 512) bf16 channels-last -------------
__global__ __launch_bounds__(256) void conv0_k(const float* __restrict__ x,
                                               const float* __restrict__ w, bf16* Y) {
  const int b = blockIdx.y, l0 = blockIdx.x * 16;
  __shared__ float xs[14 * 33];
  const int t = threadIdx.x;
  for (int i = t; i < 14 * 33; i += 256) {
    int ci = i / 33, pp = i - ci * 33;
    int pos = 2 * l0 - 1 + pp;
    xs[i] = (pos >= 0 && pos < 8192) ? x[((long)b * 14 + ci) * 8192 + pos] : 0.f;
  }
  float wr0[42], wr1[42];
  const int co0 = 2 * t;
#pragma unroll
  for (int i = 0; i < 42; i++) { wr0[i] = w[co0 * 42 + i]; wr1[i] = w[co0 * 42 + 42 + i]; }
  __syncthreads();
  for (int l = 0; l < 16; l++) {
    float a0 = 0.f, a1 = 0.f;
#pragma unroll
    for (int ci = 0; ci < 14; ci++)
#pragma unroll
      for (int k = 0; k < 3; k++) {
        float xv = xs[ci * 33 + 2 * l + k];
        a0 += xv * wr0[ci * 3 + k];
        a1 += xv * wr1[ci * 3 + k];
      }
    long orow = ((long)b * 4096 + l0 + l) * 512;
    Y[orow + co0] = (bf16)a0;
    Y[orow + co0 + 1] = (bf16)a1;
  }
}

// ---------------- BN stats ----------------
__global__ void bn_stats_k(const bf16* __restrict__ Y, float* stats, int rows, int C) {
  const int c = blockIdx.x * 256 + threadIdx.x;
  const int rpb = rows / gridDim.y;
  const int r0 = blockIdx.y * rpb;
  float s = 0.f, ss = 0.f;
  const bf16* p = Y + (long)r0 * C + c;
  for (int r = 0; r < rpb; ++r) { float v = (float)(*p); s += v; ss += v * v; p += C; }
  atomicAdd(&stats[2 * c], s);
  atomicAdd(&stats[2 * c + 1], ss);
}

// ---------------- fused BN (train-mode) + exact-erf GELU (in-place capable) -------------
__global__ void bn_gelu_k(const bf16* __restrict__ Y, const float* __restrict__ stats,
                          const float* __restrict__ g, const float* __restrict__ be,
                          bf16* outB, float* outF, long n, int C, float invN) {
  long i = blockIdx.x * 256L + threadIdx.x;
  const long st = (long)gridDim.x * 256;
  for (; i < n; i += st) {
    int c = (int)(i % C);
    float m = stats[2 * c] * invN;
    float var = stats[2 * c + 1] * invN - m * m;
    float rs = rsqrtf(fmaxf(var, 0.f) + 1e-5f);
    float xn = ((float)Y[i] - m) * rs * g[c] + be[c];
    float ge = 0.5f * xn * (1.f + erff(xn * 0.70710678118f));
    outB[i] = (bf16)ge;
    if (outF) outF[i] = ge;
  }
}

// ---------------- LayerNorm over E=1536 ----------------
__global__ __launch_bounds__(256) void ln_k(const float* __restrict__ in,
                                            const float* __restrict__ g,
                                            const float* __restrict__ b,
                                            float* outF, bf16* outB) {
  const int row = blockIdx.x, t = threadIdx.x;
  const float* r = in + (long)row * 1536;
  float v[6]; float s = 0.f;
#pragma unroll
  for (int i = 0; i < 6; i++) { v[i] = r[t + 256 * i]; s += v[i]; }
  __shared__ float red[256];
  red[t] = s; __syncthreads();
#pragma unroll
  for (int o = 128; o > 0; o >>= 1) { if (t < o) red[t] += red[t + o]; __syncthreads(); }
  const float mean = red[0] * (1.f / 1536.f);
  __syncthreads();
  float ss = 0.f;
#pragma unroll
  for (int i = 0; i < 6; i++) { float d = v[i] - mean; ss += d * d; }
  red[t] = ss; __syncthreads();
#pragma unroll
  for (int o = 128; o > 0; o >>= 1) { if (t < o) red[t] += red[t + o]; __syncthreads(); }
  const float rstd = rsqrtf(red[0] * (1.f / 1536.f) + 1e-5f);
#pragma unroll
  for (int i = 0; i < 6; i++) {
    int c = t + 256 * i;
    float o_ = (v[i] - mean) * rstd * g[c] + b[c];
    if (outF) outF[(long)row * 1536 + c] = o_;
    if (outB) outB[(long)row * 1536 + c] = (bf16)o_;
  }
}

// ---------------- softmax over rows of 256 (one wave per row) ----------------
__global__ void softmax_k(const float* __restrict__ sc, bf16* P) {
  const int row = blockIdx.x * 4 + (threadIdx.x >> 6);
  const int lane = threadIdx.x & 63;
  const float* r = sc + (long)row * 256;
  float v0 = r[lane], v1 = r[lane + 64], v2 = r[lane + 128], v3 = r[lane + 192];
  float mx = fmaxf(fmaxf(v0, v1), fmaxf(v2, v3));
  for (int m = 32; m > 0; m >>= 1) mx = fmaxf(mx, __shfl_xor(mx, m));
  v0 = expf(v0 - mx); v1 = expf(v1 - mx); v2 = expf(v2 - mx); v3 = expf(v3 - mx);
  float s = v0 + v1 + v2 + v3;
  for (int m = 32; m > 0; m >>= 1) s += __shfl_xor(s, m);
  const float inv = 1.f / s;
  bf16* o = P + (long)row * 256;
  o[lane] = (bf16)(v0 * inv); o[lane + 64] = (bf16)(v1 * inv);
  o[lane + 128] = (bf16)(v2 * inv); o[lane + 192] = (bf16)(v3 * inv);
}

// ---------------- packing (per-layer, reused buffers) ----------------
__global__ void zero_k(float* p, int n) {
  int i = blockIdx.x * 256 + threadIdx.x;
  if (i < n) p[i] = 0.f;
}

__global__ void pack_qkv_k(const float* wq, const float* wk, const float* wv, bf16* out) {
  const int c = blockIdx.x * 256 + threadIdx.x;   // 0..1535
  const int r = blockIdx.y;                        // 0..4607
  const float* src; int rr;
  if (r < 1536) { src = wq; rr = r; }
  else if (r < 3072) { src = wk; rr = r - 1536; }
  else { src = wv; rr = r - 3072; }
  out[(long)r * 1536 + c] = (bf16)src[(long)rr * 1536 + c];
}

__global__ void cast_k(const float* in, bf16* out, long n) {
  long i = blockIdx.x * 256L + threadIdx.x;
  const long st = (long)gridDim.x * 256;
  for (; i < n; i += st) out[i] = (bf16)in[i];
}

__global__ void pack_w1_k(const float* w1, bf16* out) {
  const int c = blockIdx.x * 256 + threadIdx.x;
  const int r = blockIdx.y;                        // 0..3327
  float v = (r < 3076) ? w1[(long)r * 1536 + c] : 0.f;
  out[(long)r * 1536 + c] = (bf16)v;
}

__global__ void pack_w2_k(const float* w2, bf16* out) {
  const int c = blockIdx.x * 128 + threadIdx.x;    // 0..3327
  const int r = blockIdx.y;
  float v = (c < 3076) ? w2[(long)r * 3076 + c] : 0.f;
  out[(long)r * 3328 + c] = (bf16)v;
}

__global__ void pack_b1_k(const float* b1, float* out) {
  const int c = blockIdx.x * 128 + threadIdx.x;
  const int l = blockIdx.y;
  out[l * 3328 + c] = (c < 3076) ? b1[l * 3076 + c] : 0.f;
}

// conv weight: (Cout, 512, 3) fp32 -> (Cout, 3*512) bf16, kappa = k*512+ci
__global__ void pack_conv_k(const float* w, bf16* out) {
  const int co = blockIdx.x;
  for (int i = threadIdx.x; i < 1536; i += 256) {
    int k = i >> 9, ci = i & 511;
    out[(long)co * 1536 + i] = (bf16)w[(co * 512 + ci) * 3 + k];
  }
}

// =====================================================================================
extern "C" void kernel_launch(void* const* d_in, const int* in_sizes, int n_in,
                              void* d_out, int out_size, void* d_ws, size_t ws_size,
                              hipStream_t stream) {
  const float* x_in = (const float*)d_in[0];
  const float *cw[5], *gg[5], *bb[5];
  for (int i = 0; i < 5; i++) {
    cw[i] = (const float*)d_in[1 + 4 * i];
    gg[i] = (const float*)d_in[3 + 4 * i];
    bb[i] = (const float*)d_in[4 + 4 * i];
  }
  const float* wq = (const float*)d_in[21];
  const float* wk = (const float*)d_in[22];
  const float* wv = (const float*)d_in[23];
  const float* wo = (const float*)d_in[24];
  const float* w1 = (const float*)d_in[25];
  const float* b1 = (const float*)d_in[26];
  const float* w2 = (const float*)d_in[27];
  const float* b2 = (const float*)d_in[28];
  const float* ln1g = (const float*)d_in[29];
  const float* ln1b = (const float*)d_in[30];
  const float* ln2g = (const float*)d_in[31];
  const float* ln2b = (const float*)d_in[32];

  char* ws = (char*)d_ws;
  size_t off = 0;
  auto alloc = [&](size_t bytes) -> char* {
    off = (off + 255) & ~(size_t)255;
    char* p = ws + off; off += bytes; return p;
  };
  // ---- small fixed buffers ----
  bf16* zp = (bf16*)alloc(256);
  float* stats = (float*)alloc(3072 * 4);
  float* b1p = (float*)alloc(8L * 3328 * 4);
  // ---- per-layer weight buffers (re-packed each layer) ----
  bf16* wqkv_l = (bf16*)alloc(4608L * 1536 * 2);   // 14.2 MB
  bf16* wo_l   = (bf16*)alloc(1536L * 1536 * 2);   //  4.7 MB
  bf16* w1_l   = (bf16*)alloc(3328L * 1536 * 2);   // 10.2 MB
  bf16* w2_l   = (bf16*)alloc(1536L * 3328 * 2);   // 10.2 MB
  bf16* wconv  = (bf16*)alloc(1536L * 1536 * 2);   //  4.7 MB (per-conv)
  // ---- big aliased activation buffers ----
  char* A = alloc(134217728);                      // 134.2 MB
  char* Bq = alloc(67108864);                      //  67.1 MB
  bf16* xb = (bf16*)alloc(8192L * 1536 * 2);       //  25.2 MB
  float* xf = (float*)d_out;

  // attn-phase aliases
  bf16*  vtb    = (bf16*)A;                        // [0, 33.5M)
  float* scores = (float*)(A + 33554432);          // [33.5M, 100.7M)
  bf16*  P      = (bf16*)(A + 100663296);          // [100.7M, 134.2M)
  bf16*  qb     = (bf16*)Bq;                       // [0, 25.2M)
  bf16*  kb     = (bf16*)(Bq + 25165824);          // [25.2M, 50.3M)
  bf16*  ob     = (bf16*)Bq;                       // overwrites q (dead after QK)
  // ffn-phase aliases
  float* rf  = (float*)A;                          // [0, 50.3M)
  bf16*  hb  = (bf16*)(A + 50331648);              // [50.3M, 75.5M)
  bf16*  mid = (bf16*)(A + 75497472);              // [75.5M, 130.0M) 8192x3328 bf16
  float* hf  = (float*)Bq;                         // [0, 50.3M)
  // conv-phase aliases
  bf16* cY0 = (bf16*)A;    // conv0 out 131072x512
  bf16* cY1 = (bf16*)Bq;   // conv1 out 65536x512
  bf16* cY2 = (bf16*)A;    // conv2 out 32768x512
  bf16* cY3 = (bf16*)Bq;   // conv3 out 16384x512
  bf16* cY4 = (bf16*)A;    // conv4 out 8192x1536

  zero_k<<<1, 256, 0, stream>>>((float*)zp, 64);
  pack_b1_k<<<dim3(26, 8), 128, 0, stream>>>(b1, b1p);

  conv0_k<<<dim3(256, 32), 256, 0, stream>>>(x_in, cw[0], cY0);

  auto bn = [&](const bf16* Y, bf16* outB, float* outF, int rows, int C,
                const float* g_, const float* be_) {
    zero_k<<<12, 256, 0, stream>>>(stats, 3072);
    bn_stats_k<<<dim3(C / 256, 256), 256, 0, stream>>>(Y, stats, rows, C);
    bn_gelu_k<<<4096, 256, 0, stream>>>(Y, stats, g_, be_, outB, outF,
                                        (long)rows * C, C, 1.f / (float)rows);
  };
  auto conv_gemm = [&](const bf16* Gin, const float* wsrc, int Cout, bf16* Yout,
                       int M, int N, int LoutShift, int Lin) {
    pack_conv_k<<<Cout, 256, 0, stream>>>(wsrc, wconv);
    GArgs a{}; a.A = Gin; a.B = wconv; a.Cb = Yout;
    a.K = 1536; a.ldb = 1536; a.ldc = N; a.scale = 1.f;
    a.LoutShift = LoutShift; a.Lin = Lin; a.zp = zp;
    gemm256_k<EPI_BF16, true><<<dim3(N / 256, M / 256, 1), 512, 0, stream>>>(a);
  };

  bn(cY0, cY0, nullptr, 131072, 512, gg[0], bb[0]);          // in-place BN+GELU
  conv_gemm(cY0, cw[1], 512, cY1, 65536, 512, 11, 4096);
  bn(cY1, cY1, nullptr, 65536, 512, gg[1], bb[1]);
  conv_gemm(cY1, cw[2], 512, cY2, 32768, 512, 10, 2048);
  bn(cY2, cY2, nullptr, 32768, 512, gg[2], bb[2]);
  conv_gemm(cY2, cw[3], 512, cY3, 16384, 512, 9, 1024);
  bn(cY3, cY3, nullptr, 16384, 512, gg[3], bb[3]);
  conv_gemm(cY3, cw[4], 1536, cY4, 8192, 1536, 8, 512);
  bn(cY4, xb, xf, 8192, 1536, gg[4], bb[4]);                 // -> (B,S,E) bf16 + fp32

  for (int l = 0; l < 8; l++) {
    // per-layer weight packing (stream-serialized, reused buffers)
    pack_qkv_k<<<dim3(6, 4608), 256, 0, stream>>>(wq + (long)l * 1536 * 1536,
                                                  wk + (long)l * 1536 * 1536,
                                                  wv + (long)l * 1536 * 1536, wqkv_l);
    cast_k<<<2048, 256, 0, stream>>>(wo + (long)l * 1536 * 1536, wo_l, 1536L * 1536);
    pack_w1_k<<<dim3(6, 3328), 256, 0, stream>>>(w1 + (long)l * 3076 * 1536, w1_l);
    pack_w2_k<<<dim3(26, 1536), 128, 0, stream>>>(w2 + (long)l * 1536 * 3076, w2_l);

    { // fused QKV projection, scatter into q/k (bh,s,d) and vt (bh,d,s)
      GArgs a{}; a.A = xb; a.B = wqkv_l;
      a.K = 1536; a.lda = 1536; a.ldb = 1536; a.scale = 1.f;
      a.q = qb; a.k = kb; a.vt = vtb;
      gemm256_k<EPI_QKV, false><<<dim3(18, 32, 1), 512, 0, stream>>>(a);
    }
    { // scores = Q K^T / sqrt(192), batched over 256 (b,h)
      GArgs a{}; a.A = qb; a.B = kb; a.Cf = scores;
      a.sA = 49152; a.sB = 49152; a.sC = 65536;
      a.K = 192; a.lda = 192; a.ldb = 192; a.ldc = 256;
      a.scale = 0.07216878364870323f;
      gemm_k<EPI_F32, false><<<dim3(2, 2, 256), 256, 0, stream>>>(a);
    }
    softmax_k<<<16384, 256, 0, stream>>>(scores, P);
    { // O = P V via vt; scatter into ob (b,s,e)
      GArgs a{}; a.A = P; a.B = vtb; a.sA = 65536; a.sB = 65536;
      a.K = 256; a.lda = 256; a.ldb = 256; a.scale = 1.f; a.o = ob;
      gemm_k<EPI_OSC, false><<<dim3(2, 2, 256), 256, 0, stream>>>(a);
    }
    { // rf = ob @ wo^T + xf
      GArgs a{}; a.A = ob; a.B = wo_l; a.Cf = rf;
      a.K = 1536; a.lda = 1536; a.ldb = 1536; a.ldc = 1536; a.scale = 1.f;
      a.bias = nullptr; a.res = xf;
      gemm256_k<EPI_RES, false><<<dim3(6, 32, 1), 512, 0, stream>>>(a);
    }
    ln_k<<<8192, 256, 0, stream>>>(rf, ln1g + l * 1536, ln1b + l * 1536, hf, hb);
    { // mid = relu(hb @ w1^T + b1), N padded to 3328
      GArgs a{}; a.A = hb; a.B = w1_l; a.Cb = mid;
      a.K = 1536; a.lda = 1536; a.ldb = 1536; a.ldc = 3328; a.scale = 1.f;
      a.bias = b1p + l * 3328;
      gemm256_k<EPI_RELU, false><<<dim3(13, 32, 1), 512, 0, stream>>>(a);
    }
    { // rf = mid @ w2^T + b2 + hf
      GArgs a{}; a.A = mid; a.B = w2_l; a.Cf = rf;
      a.K = 3328; a.lda = 3328; a.ldb = 3328; a.ldc = 1536; a.scale = 1.f;
      a.bias = b2 + l * 1536; a.res = hf;
      gemm256_k<EPI_RES, false><<<dim3(6, 32, 1), 512, 0, stream>>>(a);
    }
    if (l < 7)
      ln_k<<<8192, 256, 0, stream>>>(rf, ln2g + l * 1536, ln2b + l * 1536, xf, xb);
    else
      ln_k<<<8192, 256, 0, stream>>>(rf, ln2g + l * 1536, ln2b + l * 1536,
                                     (float*)d_out, nullptr);
  }
}